// Round 12
// baseline (389.413 us; speedup 1.0000x reference)
//
#include <hip/hip_runtime.h>
#include <math.h>

typedef __bf16 bf16;
typedef __attribute__((ext_vector_type(2))) __bf16 bf16x2;
typedef __attribute__((ext_vector_type(4))) __bf16 bf16x4;
typedef __attribute__((ext_vector_type(8))) __bf16 bf16x8;
typedef __attribute__((ext_vector_type(4))) float f32x4;

#define D_MODEL 1024
#define NH 16
#define DP 64
#define BB 2
#define SEQ 2048
#define TOK 4096   // B*S
#define FFD 4096
#define AST 72     // attn LDS row stride (elems); 36-dword stride = 2-way (free)

// ---- async global->LDS (wave-uniform LDS base + lane*16, m97 pattern) ----
__device__ __forceinline__ void async16(bf16* lds, const bf16* g) {
    __builtin_amdgcn_global_load_lds(
        (__attribute__((address_space(1))) void*)g,
        (__attribute__((address_space(3))) void*)lds, 16, 0, 0);
}

__device__ __forceinline__ f32x4 mfma16(bf16x8 a, bf16x8 b, f32x4 c) {
    return __builtin_amdgcn_mfma_f32_16x16x32_bf16(a, b, c, 0, 0, 0);
}

// ---- XCD-chunked bijective block swizzle (T1). Requires nwg % 8 == 0. ----
__device__ __forceinline__ void xcd_swz(int& bx, int& by, int& bz) {
    const int gx = gridDim.x, gy = gridDim.y;
    const int nwg = gx * gy * gridDim.z;
    const int orig = (blockIdx.z * gy + blockIdx.y) * gx + blockIdx.x;
    const int q = nwg >> 3;
    const int n = (orig & 7) * q + (orig >> 3);
    bx = n % gx;
    const int r = n / gx;
    by = r % gy;
    bz = r / gy;
}

// ==== fused weight-conversion + first LayerNorm (one dispatch) =============
struct CvtLnArgs {
    const float4* in[6];
    bf16x4* out[6];
    const float* x;
    const float* g;
    const float* be;
    bf16* xn;
};
__global__ __launch_bounds__(256) void cvt_ln(CvtLnArgs a)
{
    const int blk = blockIdx.x;
    const int t = threadIdx.x;
    if (blk < 12288) {
        const int i = blk * 256 + t;   // [0, 3*2^20)
        int seg, idx;
        if (i < (1 << 20)) { seg = i >> 18; idx = i & ((1 << 18) - 1); }
        else {
            const int j = i - (1 << 20);
            seg = 4 + (j >> 20); idx = j & ((1 << 20) - 1);
        }
        const float4 v = a.in[seg][idx];
        bf16x4 o; o[0] = (bf16)v.x; o[1] = (bf16)v.y; o[2] = (bf16)v.z; o[3] = (bf16)v.w;
        a.out[seg][idx] = o;
        return;
    }
    // ---- LN1 (fp32 input, unbiased std, eps on std) ----
    const size_t row = blk - 12288;
    const float* x = a.x + row * D_MODEL;
    const float4 xv = *(const float4*)(x + t * 4);
    const float v0 = xv.x, v1 = xv.y, v2 = xv.z, v3 = xv.w;
    float s  = v0 + v1 + v2 + v3;
    float ss = v0*v0 + v1*v1 + v2*v2 + v3*v3;
    #pragma unroll
    for (int off = 32; off > 0; off >>= 1) {
        s  += __shfl_down(s, off);
        ss += __shfl_down(ss, off);
    }
    __shared__ float rs[4], rss[4];
    if ((t & 63) == 0) { rs[t >> 6] = s; rss[t >> 6] = ss; }
    __syncthreads();
    const float S  = rs[0] + rs[1] + rs[2] + rs[3];
    const float SS = rss[0] + rss[1] + rss[2] + rss[3];
    const float mean = S * (1.0f / 1024.0f);
    const float var  = fmaxf((SS - S * mean) * (1.0f / 1023.0f), 0.0f);
    const float inv  = 1.0f / (sqrtf(var) + 1e-6f);
    const float4 gv = *(const float4*)(a.g  + t * 4);
    const float4 bv = *(const float4*)(a.be + t * 4);
    bf16x4 ov;
    ov[0] = (bf16)(gv.x * ((v0 - mean) * inv) + bv.x);
    ov[1] = (bf16)(gv.y * ((v1 - mean) * inv) + bv.y);
    ov[2] = (bf16)(gv.z * ((v2 - mean) * inv) + bv.z);
    ov[3] = (bf16)(gv.w * ((v3 - mean) * inv) + bv.w);
    *(bf16x4*)(a.xn + row * D_MODEL + t * 4) = ov;
}

// ======================= LayerNorm (unbiased std, eps on std) ==============
template<typename TIN>
__global__ __launch_bounds__(256) void ln_kernel(
    const TIN* __restrict__ in, const float* __restrict__ g,
    const float* __restrict__ be, bf16* __restrict__ out)
{
    const size_t row = blockIdx.x;
    const int t = threadIdx.x;
    const TIN* x = in + row * D_MODEL;

    float v0, v1, v2, v3;
    if constexpr (sizeof(TIN) == 4) {
        const float4 xv = *(const float4*)(x + t * 4);
        v0 = xv.x; v1 = xv.y; v2 = xv.z; v3 = xv.w;
    } else {
        const bf16x4 xv = *(const bf16x4*)(x + t * 4);
        v0 = (float)xv[0]; v1 = (float)xv[1]; v2 = (float)xv[2]; v3 = (float)xv[3];
    }
    float s  = v0 + v1 + v2 + v3;
    float ss = v0*v0 + v1*v1 + v2*v2 + v3*v3;
    #pragma unroll
    for (int off = 32; off > 0; off >>= 1) {
        s  += __shfl_down(s, off);
        ss += __shfl_down(ss, off);
    }
    __shared__ float rs[4], rss[4];
    if ((t & 63) == 0) { rs[t >> 6] = s; rss[t >> 6] = ss; }
    __syncthreads();
    const float S  = rs[0] + rs[1] + rs[2] + rs[3];
    const float SS = rss[0] + rss[1] + rss[2] + rss[3];
    const float mean = S * (1.0f / 1024.0f);
    const float var  = fmaxf((SS - S * mean) * (1.0f / 1023.0f), 0.0f);
    const float inv  = 1.0f / (sqrtf(var) + 1e-6f);

    const float4 gv = *(const float4*)(g  + t * 4);
    const float4 bv = *(const float4*)(be + t * 4);
    bf16x4 ov;
    ov[0] = (bf16)(gv.x * ((v0 - mean) * inv) + bv.x);
    ov[1] = (bf16)(gv.y * ((v1 - mean) * inv) + bv.y);
    ov[2] = (bf16)(gv.z * ((v2 - mean) * inv) + bv.z);
    ov[3] = (bf16)(gv.w * ((v3 - mean) * inv) + bv.w);
    *(bf16x4*)(out + row * D_MODEL + t * 4) = ov;
}

// ====== NT GEMM 128x64: dense EPI1, fc EPI2 (gelu), proj split-K EPI4 ======
// 128x64 tile = 24KB LDS -> 6 blocks/CU resident (the measured lever for
// these 2-phase latency-exposed loops; round-4 proj 2->4/CU was the big win).
template<int EPI, typename TOUT>
__global__ __launch_bounds__(256, 2) void gemm_bt64(
    const bf16* __restrict__ A, const bf16* __restrict__ W,
    const float* __restrict__ bias, const bf16* res,
    TOUT* C, TOUT* Cb, int M, int N, int K, int kchunk)
{
    int bx, by, bz; xcd_swz(bx, by, bz);
    __shared__ __align__(16) bf16 As[2][128 * 32];
    __shared__ __align__(16) bf16 Bs[2][64 * 32];
    const int t = threadIdx.x;
    const int w = t >> 6, lane = t & 63;
    const int fr = lane & 15, quad = lane >> 4;
    const int m0 = by * 128, n0 = bx * 64;
    const int kbase = bz * kchunk;
    TOUT* Cz = (EPI == 4 && bz) ? Cb : C;
    const int wm = (w >> 1) * 64, wn = (w & 1) * 32;

    const f32x4 z = {0.f, 0.f, 0.f, 0.f};
    f32x4 acc[4][2];
    #pragma unroll
    for (int i = 0; i < 4; ++i)
        #pragma unroll
        for (int j = 0; j < 2; ++j) acc[i][j] = z;

    const int nk = kchunk >> 5;
    const int srow = t >> 2, ssub = t & 3;

    #pragma unroll
    for (int call = 0; call < 2; ++call) {
        const int row = call * 64 + srow;
        async16(&As[0][(size_t)(call * 256 + w * 64) * 8],
                A + (size_t)(m0 + row) * K + kbase + ssub * 8);
    }
    async16(&Bs[0][(size_t)(w * 64) * 8],
            W + (size_t)(n0 + srow) * K + kbase + ssub * 8);
    __syncthreads();

    for (int kt = 0; kt < nk; ++kt) {
        const int cur = kt & 1;
        if (kt + 1 < nk) {
            const int k0 = kbase + ((kt + 1) << 5);
            #pragma unroll
            for (int call = 0; call < 2; ++call) {
                const int row = call * 64 + srow;
                async16(&As[cur ^ 1][(size_t)(call * 256 + w * 64) * 8],
                        A + (size_t)(m0 + row) * K + k0 + ssub * 8);
            }
            async16(&Bs[cur ^ 1][(size_t)(w * 64) * 8],
                    W + (size_t)(n0 + srow) * K + k0 + ssub * 8);
        }
        bf16x8 af[4], bfr[2];
        #pragma unroll
        for (int i = 0; i < 4; ++i)
            af[i] = *(const bf16x8*)&As[cur][(wm + i * 16 + fr) * 32 + quad * 8];
        #pragma unroll
        for (int j = 0; j < 2; ++j)
            bfr[j] = *(const bf16x8*)&Bs[cur][(wn + j * 16 + fr) * 32 + quad * 8];
        #pragma unroll
        for (int i = 0; i < 4; ++i)
            #pragma unroll
            for (int j = 0; j < 2; ++j)
                acc[i][j] = mfma16(af[i], bfr[j], acc[i][j]);
        __syncthreads();
    }

    #pragma unroll
    for (int i = 0; i < 4; ++i) {
        #pragma unroll
        for (int j = 0; j < 2; ++j) {
            #pragma unroll
            for (int r = 0; r < 4; ++r) {
                const int m = m0 + wm + i * 16 + quad * 4 + r;
                const int n = n0 + wn + j * 16 + fr;
                float v = acc[i][j][r];
                if (EPI == 1) {
                    v += bias[n];
                    v += (float)res[(size_t)m * N + n];
                    Cz[(size_t)m * N + n] = (TOUT)v;
                } else if (EPI == 2) {
                    v = 0.5f * v * (1.0f + erff(v * 0.70710678118f));
                    Cz[(size_t)m * N + n] = (TOUT)v;
                } else if (EPI == 4) {
                    Cz[(size_t)m * N + n] = (TOUT)v;   // raw partial
                } else {
                    v += (float)res[(size_t)m * N + n];
                    Cz[(size_t)m * N + n] = (TOUT)v;
                }
            }
        }
    }
}

// ====== split-K combine: out = out(p0) + p1 + res (f32 out, bf16 res) ======
__global__ __launch_bounds__(256) void combine_add(
    const float4* __restrict__ p1, const bf16x4* __restrict__ res,
    float4* __restrict__ out)
{
    const int i = blockIdx.x * 256 + threadIdx.x;   // 1M float4
    const float4 a = out[i], b = p1[i];
    const bf16x4 r = res[i];
    float4 o;
    o.x = a.x + b.x + (float)r[0];
    o.y = a.y + b.y + (float)r[1];
    o.z = a.z + b.z + (float)r[2];
    o.w = a.w + b.w + (float)r[3];
    out[i] = o;
}

// ============ Fused QKV GEMM: 128x64 tiles, grid (48, 32) ==================
// 1536 blocks -> 6 blocks/CU (was 3 at 128x128). A-panel (256KB) L2-resident
// per XCD chunk, so the doubled A-refetch is absorbed.
__global__ __launch_bounds__(256, 2) void gemm_qkv(
    const bf16* __restrict__ A,
    const bf16* __restrict__ wq, const bf16* __restrict__ wk,
    const bf16* __restrict__ wvv,
    const float* __restrict__ bq, const float* __restrict__ bk,
    const float* __restrict__ bv,
    bf16* __restrict__ outq, bf16* __restrict__ outk, bf16* __restrict__ outv)
{
    int bx, by, bz; xcd_swz(bx, by, bz);   // nwg = 1536, %8 == 0
    const int sel = bx >> 4;               // 16 n-tiles of 64 per weight
    const bf16* W = (sel == 0) ? wq : ((sel == 1) ? wk : wvv);
    const float* bias = (sel == 0) ? bq : ((sel == 1) ? bk : bv);
    bf16* C = (sel == 0) ? outq : ((sel == 1) ? outk : outv);
    const float scale = (sel == 0) ? 0.125f : 1.0f;
    const int K = D_MODEL;

    __shared__ __align__(16) bf16 As[2][128 * 32];
    __shared__ __align__(16) bf16 Bs[2][64 * 32];
    const int t = threadIdx.x;
    const int w = t >> 6, lane = t & 63;
    const int fr = lane & 15, quad = lane >> 4;
    const int m0 = by * 128, n0 = (bx & 15) * 64;
    const int wm = (w >> 1) * 64, wn = (w & 1) * 32;

    const f32x4 z = {0.f, 0.f, 0.f, 0.f};
    f32x4 acc[4][2];
    #pragma unroll
    for (int i = 0; i < 4; ++i)
        #pragma unroll
        for (int j = 0; j < 2; ++j) acc[i][j] = z;

    const int nk = D_MODEL >> 5;
    const int srow = t >> 2, ssub = t & 3;

    #pragma unroll
    for (int call = 0; call < 2; ++call) {
        const int row = call * 64 + srow;
        async16(&As[0][(size_t)(call * 256 + w * 64) * 8],
                A + (size_t)(m0 + row) * K + ssub * 8);
    }
    async16(&Bs[0][(size_t)(w * 64) * 8],
            W + (size_t)(n0 + srow) * K + ssub * 8);
    __syncthreads();

    for (int kt = 0; kt < nk; ++kt) {
        const int cur = kt & 1;
        if (kt + 1 < nk) {
            const int k0 = (kt + 1) << 5;
            #pragma unroll
            for (int call = 0; call < 2; ++call) {
                const int row = call * 64 + srow;
                async16(&As[cur ^ 1][(size_t)(call * 256 + w * 64) * 8],
                        A + (size_t)(m0 + row) * K + k0 + ssub * 8);
            }
            async16(&Bs[cur ^ 1][(size_t)(w * 64) * 8],
                    W + (size_t)(n0 + srow) * K + k0 + ssub * 8);
        }
        bf16x8 af[4], bfr[2];
        #pragma unroll
        for (int i = 0; i < 4; ++i)
            af[i] = *(const bf16x8*)&As[cur][(wm + i * 16 + fr) * 32 + quad * 8];
        #pragma unroll
        for (int j = 0; j < 2; ++j)
            bfr[j] = *(const bf16x8*)&Bs[cur][(wn + j * 16 + fr) * 32 + quad * 8];
        #pragma unroll
        for (int i = 0; i < 4; ++i)
            #pragma unroll
            for (int j = 0; j < 2; ++j)
                acc[i][j] = mfma16(af[i], bfr[j], acc[i][j]);
        __syncthreads();
    }

    #pragma unroll
    for (int i = 0; i < 4; ++i)
        #pragma unroll
        for (int j = 0; j < 2; ++j)
            #pragma unroll
            for (int r = 0; r < 4; ++r) {
                const int m = m0 + wm + i * 16 + quad * 4 + r;
                const int n = n0 + wn + j * 16 + fr;
                const float vv = (acc[i][j][r] + bias[n]) * scale;
                const int b = m >> 11, s = m & 2047, h = n >> 6, d = n & 63;
                C[(((size_t)(b * NH + h)) * SEQ + s) * DP + d] = (bf16)vv;
            }
}

// ======================= Flash attention (causal) ==========================
// ROUND-7 VERSION (57.4/58.0 us measured — best). Grid (32, 32), one
// q-tile/block, XCD-chunked, longest-first. Swapped QK^T (mfma(K,Q));
// PV as O^T (mfma(V^T,P)) -> mi/li lane-local. Double-buffered K/V,
// AST=72, launch_bounds(256,3): VGPR 68, no spill.
__global__ __launch_bounds__(256, 3) void attn_kernel(
    const bf16* __restrict__ q, const bf16* __restrict__ k,
    const bf16* __restrict__ v, bf16* __restrict__ ctx)
{
    __shared__ __align__(16) bf16 Ks[2][64 * AST];
    __shared__ __align__(16) bf16 VsT[2][64 * AST];
    __shared__ __align__(16) bf16 Ps[4][16 * AST];
    const int t = threadIdx.x, wv = t >> 6, lane = t & 63;
    const int fr = lane & 15, quad = lane >> 4;
    const int id = blockIdx.y * 32 + blockIdx.x;           // [0,1024)
    const int nid = (id & 7) * 128 + (id >> 3);            // XCD-chunked
    const int bh = nid >> 5;
    const int qt = 31 - (nid & 31);                        // longest first
    const size_t base = (size_t)bh * SEQ * DP;
    const int b = bh >> 4, hh = bh & 15;
    const f32x4 z = {0.f, 0.f, 0.f, 0.f};
    const int krow = t >> 2, kd0 = (t & 3) * 16;
    const int pp = t & 31, c0 = (t >> 5) * 8;

    const int q0 = qt * 64, qr0 = q0 + wv * 16;
    const int nkt = qt + 1;
    const int myq = qr0 + fr;    // this lane's q-row (swapped layout)

    bf16x8 qf[2];
    #pragma unroll
    for (int c = 0; c < 2; ++c)
        qf[c] = *(const bf16x8*)(q + base + (size_t)myq * DP + c * 32 + quad * 8);

    bf16x8 k0r, k1r, v0r, v1r;
    {
        const bf16* kp = k + base + (size_t)krow * DP + kd0;
        k0r = *(const bf16x8*)kp; k1r = *(const bf16x8*)(kp + 8);
        const bf16* vp = v + base + (size_t)(2 * pp) * DP + c0;
        v0r = *(const bf16x8*)vp; v1r = *(const bf16x8*)(vp + DP);
    }

    f32x4 o[4] = {z, z, z, z};
    float mi = -1e30f, li = 0.f;

    for (int kt = 0; kt < nkt; ++kt) {
        const int cur = kt & 1;
        const int kk0 = kt * 64;
        *(bf16x8*)&Ks[cur][krow * AST + kd0]     = k0r;
        *(bf16x8*)&Ks[cur][krow * AST + kd0 + 8] = k1r;
        #pragma unroll
        for (int j = 0; j < 8; ++j) {
            bf16x2 pr; pr[0] = v0r[j]; pr[1] = v1r[j];
            *(bf16x2*)&VsT[cur][(c0 + j) * AST + 2 * pp] = pr;
        }
        __syncthreads();
        if (kt + 1 < nkt) {
            const bf16* kp = k + base + (size_t)(kk0 + 64 + krow) * DP + kd0;
            k0r = *(const bf16x8*)kp; k1r = *(const bf16x8*)(kp + 8);
            const bf16* vp = v + base + (size_t)(kk0 + 64 + 2 * pp) * DP + c0;
            v0r = *(const bf16x8*)vp; v1r = *(const bf16x8*)(vp + DP);
        }

        // QK^T swapped: sa[nb][r] = score[key = kk0+nb*16+quad*4+r][q = myq]
        f32x4 sa[4] = {z, z, z, z};
        __builtin_amdgcn_s_setprio(1);
        #pragma unroll
        for (int nb = 0; nb < 4; ++nb)
            #pragma unroll
            for (int c = 0; c < 2; ++c) {
                const bf16x8 kf = *(const bf16x8*)&Ks[cur][(nb * 16 + fr) * AST + c * 32 + quad * 8];
                sa[nb] = mfma16(kf, qf[c], sa[nb]);
            }
        __builtin_amdgcn_s_setprio(0);

        float p[4][4];
        float rmax = -1e30f;
        if (kk0 + 63 > qr0) {   // wave-uniform: tile may touch the mask
            #pragma unroll
            for (int nb = 0; nb < 4; ++nb)
                #pragma unroll
                for (int r = 0; r < 4; ++r) {
                    const int key = kk0 + nb * 16 + quad * 4 + r;
                    float sv = sa[nb][r];
                    if (key > myq) sv += -1e9f;
                    p[nb][r] = sv;
                    rmax = fmaxf(rmax, sv);
                }
        } else {                // fully unmasked tile
            #pragma unroll
            for (int nb = 0; nb < 4; ++nb)
                #pragma unroll
                for (int r = 0; r < 4; ++r) {
                    p[nb][r] = sa[nb][r];
                    rmax = fmaxf(rmax, sa[nb][r]);
                }
        }
        rmax = fmaxf(rmax, __shfl_xor(rmax, 16));
        rmax = fmaxf(rmax, __shfl_xor(rmax, 32));

        // T13 defer-max: rescale only when needed (wave-uniform branch).
        const bool need = !__all(rmax - mi <= 8.0f);
        if (need) {
            const float nm = fmaxf(mi, rmax);
            const float alpha = __expf(mi - nm);
            mi = nm;
            li *= alpha;
            #pragma unroll
            for (int db = 0; db < 4; ++db)
                #pragma unroll
                for (int r = 0; r < 4; ++r) o[db][r] *= alpha;
        }
        float ps = 0.f;
        #pragma unroll
        for (int nb = 0; nb < 4; ++nb)
            #pragma unroll
            for (int r = 0; r < 4; ++r) {
                const float e = __expf(p[nb][r] - mi);
                p[nb][r] = e;
                ps += e;
            }
        ps += __shfl_xor(ps, 16);
        ps += __shfl_xor(ps, 32);
        li += ps;

        // P store: row = q-local (fr), col = key-local (nb*16+quad*4+r).
        #pragma unroll
        for (int nb = 0; nb < 4; ++nb) {
            bf16x4 pw;
            pw[0] = (bf16)p[nb][0]; pw[1] = (bf16)p[nb][1];
            pw[2] = (bf16)p[nb][2]; pw[3] = (bf16)p[nb][3];
            *(bf16x4*)&Ps[wv][fr * AST + nb * 16 + quad * 4] = pw;
        }

        bf16x8 pf[2];
        #pragma unroll
        for (int c = 0; c < 2; ++c)
            pf[c] = *(const bf16x8*)&Ps[wv][fr * AST + c * 32 + quad * 8];
        // PV as O^T = V^T . P^T: D row = d-local (quad*4+r), col = q (fr).
        __builtin_amdgcn_s_setprio(1);
        #pragma unroll
        for (int db = 0; db < 4; ++db)
            #pragma unroll
            for (int c = 0; c < 2; ++c) {
                const bf16x8 vf = *(const bf16x8*)&VsT[cur][(db * 16 + fr) * AST + c * 32 + quad * 8];
                o[db] = mfma16(vf, pf[c], o[db]);
            }
        __builtin_amdgcn_s_setprio(0);
    }

    const float inv_li = 1.0f / li;
    #pragma unroll
    for (int db = 0; db < 4; ++db) {
        bf16x4 ov;
        #pragma unroll
        for (int r = 0; r < 4; ++r) ov[r] = (bf16)(o[db][r] * inv_li);
        const int d = db * 16 + quad * 4;
        *(bf16x4*)&ctx[((size_t)(b * SEQ + myq)) * D_MODEL + hh * DP + d] = ov;
    }
}

// ======================= launcher ==========================================
extern "C" void kernel_launch(void* const* d_in, const int* in_sizes, int n_in,
                              void* d_out, int out_size, void* d_ws, size_t ws_size,
                              hipStream_t stream) {
    const float* x       = (const float*)d_in[0];
    const float* wq_w    = (const float*)d_in[2];
    const float* wq_b    = (const float*)d_in[3];
    const float* wk_w    = (const float*)d_in[4];
    const float* wk_b    = (const float*)d_in[5];
    const float* wv_w    = (const float*)d_in[6];
    const float* wv_b    = (const float*)d_in[7];
    const float* dense_w = (const float*)d_in[8];
    const float* dense_b = (const float*)d_in[9];
    const float* gamma1  = (const float*)d_in[10];
    const float* beta1   = (const float*)d_in[11];
    const float* gamma2  = (const float*)d_in[12];
    const float* beta2   = (const float*)d_in[13];
    const float* fc_w    = (const float*)d_in[14];
    const float* proj_w  = (const float*)d_in[15];
    float* out = (float*)d_out;

    bf16* ws = (bf16*)d_ws;
    const size_t M1 = (size_t)1 << 20;
    bf16* xn   = ws;               // -> h -> hn in place   bytes [0,8MB)
    bf16* qb   = ws + 4 * M1;      // bytes [8,16MB)
    bf16* kb   = ws + 8 * M1;      // bytes [16,24MB)
    bf16* vb   = ws + 12 * M1;     // bytes [24,32MB)
    bf16* ctx  = ws + 16 * M1;     // bytes [32,40MB)
    bf16* ff1  = qb;               // 16M elems overlay: bytes [8,40MB)
    bf16* wqc  = ws + 20 * M1;     // bytes [40,42MB)
    bf16* wkc  = ws + 21 * M1;
    bf16* wvc  = ws + 22 * M1;
    bf16* wdc  = ws + 23 * M1;
    bf16* fcc  = ws + 24 * M1;     // bytes [48,56MB)
    bf16* prjc = ws + 28 * M1;     // bytes [56,64MB)
    bf16* h = xn, *hn = xn;
    // split-K partial 1: 16MB f32 at bytes [40,56MB) = wqc..fcc, all dead at
    // proj time. partial 0 goes to `out`. No overlap with ff1 or prjc.
    float* part1 = (float*)(ws + 20 * M1);

    // fused weight pre-conversion + LN1, one dispatch
    CvtLnArgs ca;
    ca.in[0] = (const float4*)wq_w;    ca.out[0] = (bf16x4*)wqc;
    ca.in[1] = (const float4*)wk_w;    ca.out[1] = (bf16x4*)wkc;
    ca.in[2] = (const float4*)wv_w;    ca.out[2] = (bf16x4*)wvc;
    ca.in[3] = (const float4*)dense_w; ca.out[3] = (bf16x4*)wdc;
    ca.in[4] = (const float4*)fc_w;    ca.out[4] = (bf16x4*)fcc;
    ca.in[5] = (const float4*)proj_w;  ca.out[5] = (bf16x4*)prjc;
    ca.x = x; ca.g = gamma1; ca.be = beta1; ca.xn = xn;
    cvt_ln<<<12288 + TOK, 256, 0, stream>>>(ca);

    gemm_qkv<<<dim3(48, 32), 256, 0, stream>>>(xn, wqc, wkc, wvc,
                                               wq_b, wk_b, wv_b, qb, kb, vb);
    attn_kernel<<<dim3(32, BB * NH), 256, 0, stream>>>(qb, kb, vb, ctx);
    gemm_bt64<1, bf16><<<dim3(16, 32), 256, 0, stream>>>(
        ctx, wdc, dense_b, xn, h, (bf16*)nullptr, TOK, D_MODEL, D_MODEL, D_MODEL);
    ln_kernel<bf16><<<TOK, 256, 0, stream>>>(h, gamma2, beta2, hn);
    // fc: 128x64 tiles, grid (64,32) = 2048 blocks = 8/CU grid, 6/CU LDS-res
    gemm_bt64<2, bf16><<<dim3(64, 32), 256, 0, stream>>>(
        hn, fcc, nullptr, nullptr, ff1, (bf16*)nullptr, TOK, FFD, D_MODEL, D_MODEL);
    // proj: split-K x2 -> f32 partials (z=0 -> out, z=1 -> part1), then combine
    gemm_bt64<4, float><<<dim3(16, 32, 2), 256, 0, stream>>>(
        ff1, prjc, nullptr, nullptr, out, part1, TOK, D_MODEL, FFD, FFD / 2);
    combine_add<<<4096, 256, 0, stream>>>(
        (const float4*)part1, (const bf16x4*)hn, (float4*)out);
}

// Round 13
// 366.116 us; speedup vs baseline: 1.0636x; 1.0636x over previous
//
#include <hip/hip_runtime.h>
#include <math.h>

typedef __bf16 bf16;
typedef __attribute__((ext_vector_type(2))) __bf16 bf16x2;
typedef __attribute__((ext_vector_type(4))) __bf16 bf16x4;
typedef __attribute__((ext_vector_type(8))) __bf16 bf16x8;
typedef __attribute__((ext_vector_type(4))) float f32x4;

#define D_MODEL 1024
#define NH 16
#define DP 64
#define BB 2
#define SEQ 2048
#define TOK 4096   // B*S
#define FFD 4096
#define AST 72     // attn LDS row stride (elems); 36-dword stride = 2-way (free)

// ---- async global->LDS (wave-uniform LDS base + lane*16, m97 pattern) ----
__device__ __forceinline__ void async16(bf16* lds, const bf16* g) {
    __builtin_amdgcn_global_load_lds(
        (__attribute__((address_space(1))) void*)g,
        (__attribute__((address_space(3))) void*)lds, 16, 0, 0);
}

__device__ __forceinline__ f32x4 mfma16(bf16x8 a, bf16x8 b, f32x4 c) {
    return __builtin_amdgcn_mfma_f32_16x16x32_bf16(a, b, c, 0, 0, 0);
}

// ---- XCD-chunked bijective block swizzle (T1). Requires nwg % 8 == 0. ----
__device__ __forceinline__ void xcd_swz(int& bx, int& by, int& bz) {
    const int gx = gridDim.x, gy = gridDim.y;
    const int nwg = gx * gy * gridDim.z;
    const int orig = (blockIdx.z * gy + blockIdx.y) * gx + blockIdx.x;
    const int q = nwg >> 3;
    const int n = (orig & 7) * q + (orig >> 3);
    bx = n % gx;
    const int r = n / gx;
    by = r % gy;
    bz = r / gy;
}

// ============ fused fp32 -> bf16 weight pre-conversion (one dispatch) ======
struct CvtArgs {
    const float4* in[6];
    bf16x4* out[6];
};
__global__ __launch_bounds__(256) void cvt_all(CvtArgs a)
{
    const int i = blockIdx.x * 256 + threadIdx.x;   // [0, 3*2^20)
    int seg, idx;
    if (i < (1 << 20)) { seg = i >> 18; idx = i & ((1 << 18) - 1); }
    else {
        const int j = i - (1 << 20);
        seg = 4 + (j >> 20); idx = j & ((1 << 20) - 1);
    }
    const float4 v = a.in[seg][idx];
    bf16x4 o; o[0] = (bf16)v.x; o[1] = (bf16)v.y; o[2] = (bf16)v.z; o[3] = (bf16)v.w;
    a.out[seg][idx] = o;
}

// ======================= LayerNorm (unbiased std, eps on std) ==============
template<typename TIN>
__global__ __launch_bounds__(256) void ln_kernel(
    const TIN* __restrict__ in, const float* __restrict__ g,
    const float* __restrict__ be, bf16* __restrict__ out)
{
    const size_t row = blockIdx.x;
    const int t = threadIdx.x;
    const TIN* x = in + row * D_MODEL;

    float v0, v1, v2, v3;
    if constexpr (sizeof(TIN) == 4) {
        const float4 xv = *(const float4*)(x + t * 4);
        v0 = xv.x; v1 = xv.y; v2 = xv.z; v3 = xv.w;
    } else {
        const bf16x4 xv = *(const bf16x4*)(x + t * 4);
        v0 = (float)xv[0]; v1 = (float)xv[1]; v2 = (float)xv[2]; v3 = (float)xv[3];
    }
    float s  = v0 + v1 + v2 + v3;
    float ss = v0*v0 + v1*v1 + v2*v2 + v3*v3;
    #pragma unroll
    for (int off = 32; off > 0; off >>= 1) {
        s  += __shfl_down(s, off);
        ss += __shfl_down(ss, off);
    }
    __shared__ float rs[4], rss[4];
    if ((t & 63) == 0) { rs[t >> 6] = s; rss[t >> 6] = ss; }
    __syncthreads();
    const float S  = rs[0] + rs[1] + rs[2] + rs[3];
    const float SS = rss[0] + rss[1] + rss[2] + rss[3];
    const float mean = S * (1.0f / 1024.0f);
    const float var  = fmaxf((SS - S * mean) * (1.0f / 1023.0f), 0.0f);
    const float inv  = 1.0f / (sqrtf(var) + 1e-6f);

    const float4 gv = *(const float4*)(g  + t * 4);
    const float4 bv = *(const float4*)(be + t * 4);
    bf16x4 ov;
    ov[0] = (bf16)(gv.x * ((v0 - mean) * inv) + bv.x);
    ov[1] = (bf16)(gv.y * ((v1 - mean) * inv) + bv.y);
    ov[2] = (bf16)(gv.z * ((v2 - mean) * inv) + bv.z);
    ov[3] = (bf16)(gv.w * ((v3 - mean) * inv) + bv.w);
    *(bf16x4*)(out + row * D_MODEL + t * 4) = ov;
}

// ====== NT GEMM 128x128: C[m,n] = sum_k A[m,k]*W[n,k] (fc: gelu) ===========
template<int EPI, typename TOUT>
__global__ __launch_bounds__(256, 2) void gemm_bt(
    const bf16* __restrict__ A, const bf16* __restrict__ W,
    const float* __restrict__ bias, const bf16* res,
    TOUT* C, int M, int N, int K, float scale)
{
    int bx, by, bz; xcd_swz(bx, by, bz);
    __shared__ __align__(16) bf16 As[2][128 * 32];
    __shared__ __align__(16) bf16 Bs[2][128 * 32];
    const int t = threadIdx.x;
    const int w = t >> 6, lane = t & 63;
    const int fr = lane & 15, quad = lane >> 4;
    const int m0 = by * 128, n0 = bx * 128;
    const int wm = (w >> 1) * 64, wn = (w & 1) * 64;

    const f32x4 z = {0.f, 0.f, 0.f, 0.f};
    f32x4 acc[4][4];
    #pragma unroll
    for (int i = 0; i < 4; ++i)
        #pragma unroll
        for (int j = 0; j < 4; ++j) acc[i][j] = z;

    const int nk = K >> 5;
    const int srow = t >> 2, ssub = t & 3;

    #pragma unroll
    for (int call = 0; call < 2; ++call) {
        const int row = call * 64 + srow;
        async16(&As[0][(size_t)(call * 256 + w * 64) * 8],
                A + (size_t)(m0 + row) * K + ssub * 8);
        async16(&Bs[0][(size_t)(call * 256 + w * 64) * 8],
                W + (size_t)(n0 + row) * K + ssub * 8);
    }
    __syncthreads();

    for (int kt = 0; kt < nk; ++kt) {
        const int cur = kt & 1;
        if (kt + 1 < nk) {
            const int k0 = (kt + 1) << 5;
            #pragma unroll
            for (int call = 0; call < 2; ++call) {
                const int row = call * 64 + srow;
                async16(&As[cur ^ 1][(size_t)(call * 256 + w * 64) * 8],
                        A + (size_t)(m0 + row) * K + k0 + ssub * 8);
                async16(&Bs[cur ^ 1][(size_t)(call * 256 + w * 64) * 8],
                        W + (size_t)(n0 + row) * K + k0 + ssub * 8);
            }
        }
        bf16x8 af[4], bfr[4];
        #pragma unroll
        for (int i = 0; i < 4; ++i)
            af[i] = *(const bf16x8*)&As[cur][(wm + i * 16 + fr) * 32 + quad * 8];
        #pragma unroll
        for (int j = 0; j < 4; ++j)
            bfr[j] = *(const bf16x8*)&Bs[cur][(wn + j * 16 + fr) * 32 + quad * 8];
        #pragma unroll
        for (int i = 0; i < 4; ++i)
            #pragma unroll
            for (int j = 0; j < 4; ++j)
                acc[i][j] = mfma16(af[i], bfr[j], acc[i][j]);
        __syncthreads();
    }

    // Epilogue. C/D layout (m89): col = lane&15, row = quad*4 + reg.
    #pragma unroll
    for (int i = 0; i < 4; ++i) {
        #pragma unroll
        for (int j = 0; j < 4; ++j) {
            #pragma unroll
            for (int r = 0; r < 4; ++r) {
                const int m = m0 + wm + i * 16 + quad * 4 + r;
                const int n = n0 + wn + j * 16 + fr;
                float v = acc[i][j][r];
                if (EPI == 1) {
                    v += bias[n];
                    v += (float)res[(size_t)m * N + n];
                    C[(size_t)m * N + n] = (TOUT)v;
                } else if (EPI == 2) {
                    v = 0.5f * v * (1.0f + erff(v * 0.70710678118f));
                    C[(size_t)m * N + n] = (TOUT)v;
                } else {
                    v += (float)res[(size_t)m * N + n];
                    C[(size_t)m * N + n] = (TOUT)v;
                }
            }
        }
    }
}

// ====== NT GEMM 128x64 (N=1024 shapes: dense EPI1, proj split-K EPI4) ======
template<int EPI, typename TOUT>
__global__ __launch_bounds__(256, 2) void gemm_bt64(
    const bf16* __restrict__ A, const bf16* __restrict__ W,
    const float* __restrict__ bias, const bf16* res,
    TOUT* C, TOUT* Cb, int M, int N, int K, int kchunk)
{
    int bx, by, bz; xcd_swz(bx, by, bz);
    __shared__ __align__(16) bf16 As[2][128 * 32];
    __shared__ __align__(16) bf16 Bs[2][64 * 32];
    const int t = threadIdx.x;
    const int w = t >> 6, lane = t & 63;
    const int fr = lane & 15, quad = lane >> 4;
    const int m0 = by * 128, n0 = bx * 64;
    const int kbase = bz * kchunk;
    TOUT* Cz = (EPI == 4 && bz) ? Cb : C;
    const int wm = (w >> 1) * 64, wn = (w & 1) * 32;

    const f32x4 z = {0.f, 0.f, 0.f, 0.f};
    f32x4 acc[4][2];
    #pragma unroll
    for (int i = 0; i < 4; ++i)
        #pragma unroll
        for (int j = 0; j < 2; ++j) acc[i][j] = z;

    const int nk = kchunk >> 5;
    const int srow = t >> 2, ssub = t & 3;

    #pragma unroll
    for (int call = 0; call < 2; ++call) {
        const int row = call * 64 + srow;
        async16(&As[0][(size_t)(call * 256 + w * 64) * 8],
                A + (size_t)(m0 + row) * K + kbase + ssub * 8);
    }
    async16(&Bs[0][(size_t)(w * 64) * 8],
            W + (size_t)(n0 + srow) * K + kbase + ssub * 8);
    __syncthreads();

    for (int kt = 0; kt < nk; ++kt) {
        const int cur = kt & 1;
        if (kt + 1 < nk) {
            const int k0 = kbase + ((kt + 1) << 5);
            #pragma unroll
            for (int call = 0; call < 2; ++call) {
                const int row = call * 64 + srow;
                async16(&As[cur ^ 1][(size_t)(call * 256 + w * 64) * 8],
                        A + (size_t)(m0 + row) * K + k0 + ssub * 8);
            }
            async16(&Bs[cur ^ 1][(size_t)(w * 64) * 8],
                    W + (size_t)(n0 + srow) * K + k0 + ssub * 8);
        }
        bf16x8 af[4], bfr[2];
        #pragma unroll
        for (int i = 0; i < 4; ++i)
            af[i] = *(const bf16x8*)&As[cur][(wm + i * 16 + fr) * 32 + quad * 8];
        #pragma unroll
        for (int j = 0; j < 2; ++j)
            bfr[j] = *(const bf16x8*)&Bs[cur][(wn + j * 16 + fr) * 32 + quad * 8];
        #pragma unroll
        for (int i = 0; i < 4; ++i)
            #pragma unroll
            for (int j = 0; j < 2; ++j)
                acc[i][j] = mfma16(af[i], bfr[j], acc[i][j]);
        __syncthreads();
    }

    #pragma unroll
    for (int i = 0; i < 4; ++i) {
        #pragma unroll
        for (int j = 0; j < 2; ++j) {
            #pragma unroll
            for (int r = 0; r < 4; ++r) {
                const int m = m0 + wm + i * 16 + quad * 4 + r;
                const int n = n0 + wn + j * 16 + fr;
                float v = acc[i][j][r];
                if (EPI == 1) {
                    v += bias[n];
                    v += (float)res[(size_t)m * N + n];
                    Cz[(size_t)m * N + n] = (TOUT)v;
                } else if (EPI == 4) {
                    Cz[(size_t)m * N + n] = (TOUT)v;   // raw partial
                } else {
                    v += (float)res[(size_t)m * N + n];
                    Cz[(size_t)m * N + n] = (TOUT)v;
                }
            }
        }
    }
}

// ====== split-K combine: out = out(p0) + p1 + res (f32 out, bf16 res) ======
__global__ __launch_bounds__(256) void combine_add(
    const float4* __restrict__ p1, const bf16x4* __restrict__ res,
    float4* __restrict__ out)
{
    const int i = blockIdx.x * 256 + threadIdx.x;   // 1M float4
    const float4 a = out[i], b = p1[i];
    const bf16x4 r = res[i];
    float4 o;
    o.x = a.x + b.x + (float)r[0];
    o.y = a.y + b.y + (float)r[1];
    o.z = a.z + b.z + (float)r[2];
    o.w = a.w + b.w + (float)r[3];
    out[i] = o;
}

// ============ Fused QKV GEMM: one dispatch, grid (24, 32) ==================
__global__ __launch_bounds__(256, 2) void gemm_qkv(
    const bf16* __restrict__ A,
    const bf16* __restrict__ wq, const bf16* __restrict__ wk,
    const bf16* __restrict__ wvv,
    const float* __restrict__ bq, const float* __restrict__ bk,
    const float* __restrict__ bv,
    bf16* __restrict__ outq, bf16* __restrict__ outk, bf16* __restrict__ outv)
{
    int bx, by, bz; xcd_swz(bx, by, bz);
    const int sel = bx >> 3;
    const bf16* W = (sel == 0) ? wq : ((sel == 1) ? wk : wvv);
    const float* bias = (sel == 0) ? bq : ((sel == 1) ? bk : bv);
    bf16* C = (sel == 0) ? outq : ((sel == 1) ? outk : outv);
    const float scale = (sel == 0) ? 0.125f : 1.0f;
    const int K = D_MODEL;

    __shared__ __align__(16) bf16 As[2][128 * 32];
    __shared__ __align__(16) bf16 Bs[2][128 * 32];
    const int t = threadIdx.x;
    const int w = t >> 6, lane = t & 63;
    const int fr = lane & 15, quad = lane >> 4;
    const int m0 = by * 128, n0 = (bx & 7) * 128;
    const int wm = (w >> 1) * 64, wn = (w & 1) * 64;

    const f32x4 z = {0.f, 0.f, 0.f, 0.f};
    f32x4 acc[4][4];
    #pragma unroll
    for (int i = 0; i < 4; ++i)
        #pragma unroll
        for (int j = 0; j < 4; ++j) acc[i][j] = z;

    const int nk = D_MODEL >> 5;
    const int srow = t >> 2, ssub = t & 3;

    #pragma unroll
    for (int call = 0; call < 2; ++call) {
        const int row = call * 64 + srow;
        async16(&As[0][(size_t)(call * 256 + w * 64) * 8],
                A + (size_t)(m0 + row) * K + ssub * 8);
        async16(&Bs[0][(size_t)(call * 256 + w * 64) * 8],
                W + (size_t)(n0 + row) * K + ssub * 8);
    }
    __syncthreads();

    for (int kt = 0; kt < nk; ++kt) {
        const int cur = kt & 1;
        if (kt + 1 < nk) {
            const int k0 = (kt + 1) << 5;
            #pragma unroll
            for (int call = 0; call < 2; ++call) {
                const int row = call * 64 + srow;
                async16(&As[cur ^ 1][(size_t)(call * 256 + w * 64) * 8],
                        A + (size_t)(m0 + row) * K + k0 + ssub * 8);
                async16(&Bs[cur ^ 1][(size_t)(call * 256 + w * 64) * 8],
                        W + (size_t)(n0 + row) * K + k0 + ssub * 8);
            }
        }
        bf16x8 af[4], bfr[4];
        #pragma unroll
        for (int i = 0; i < 4; ++i)
            af[i] = *(const bf16x8*)&As[cur][(wm + i * 16 + fr) * 32 + quad * 8];
        #pragma unroll
        for (int j = 0; j < 4; ++j)
            bfr[j] = *(const bf16x8*)&Bs[cur][(wn + j * 16 + fr) * 32 + quad * 8];
        #pragma unroll
        for (int i = 0; i < 4; ++i)
            #pragma unroll
            for (int j = 0; j < 4; ++j)
                acc[i][j] = mfma16(af[i], bfr[j], acc[i][j]);
        __syncthreads();
    }

    #pragma unroll
    for (int i = 0; i < 4; ++i)
        #pragma unroll
        for (int j = 0; j < 4; ++j)
            #pragma unroll
            for (int r = 0; r < 4; ++r) {
                const int m = m0 + wm + i * 16 + quad * 4 + r;
                const int n = n0 + wn + j * 16 + fr;
                const float vv = (acc[i][j][r] + bias[n]) * scale;
                const int b = m >> 11, s = m & 2047, h = n >> 6, d = n & 63;
                C[(((size_t)(b * NH + h)) * SEQ + s) * DP + d] = (bf16)vv;
            }
}

// ======================= Flash attention (causal) ==========================
// BEST MEASURED (57.4-58.0 us). Grid (32, 32), one q-tile/block, XCD-chunked,
// longest-first. Swapped QK^T (mfma(K,Q)); PV as O^T (mfma(V^T,P)) ->
// mi/li lane-local. Double-buffered K/V, AST=72, launch_bounds(256,3):
// VGPR 68, no spill. Single-buffer, AST=66, bounds-6 all measured WORSE.
__global__ __launch_bounds__(256, 3) void attn_kernel(
    const bf16* __restrict__ q, const bf16* __restrict__ k,
    const bf16* __restrict__ v, bf16* __restrict__ ctx)
{
    __shared__ __align__(16) bf16 Ks[2][64 * AST];
    __shared__ __align__(16) bf16 VsT[2][64 * AST];
    __shared__ __align__(16) bf16 Ps[4][16 * AST];
    const int t = threadIdx.x, wv = t >> 6, lane = t & 63;
    const int fr = lane & 15, quad = lane >> 4;
    const int id = blockIdx.y * 32 + blockIdx.x;           // [0,1024)
    const int nid = (id & 7) * 128 + (id >> 3);            // XCD-chunked
    const int bh = nid >> 5;
    const int qt = 31 - (nid & 31);                        // longest first
    const size_t base = (size_t)bh * SEQ * DP;
    const int b = bh >> 4, hh = bh & 15;
    const f32x4 z = {0.f, 0.f, 0.f, 0.f};
    const int krow = t >> 2, kd0 = (t & 3) * 16;
    const int pp = t & 31, c0 = (t >> 5) * 8;

    const int q0 = qt * 64, qr0 = q0 + wv * 16;
    const int nkt = qt + 1;
    const int myq = qr0 + fr;    // this lane's q-row (swapped layout)

    bf16x8 qf[2];
    #pragma unroll
    for (int c = 0; c < 2; ++c)
        qf[c] = *(const bf16x8*)(q + base + (size_t)myq * DP + c * 32 + quad * 8);

    bf16x8 k0r, k1r, v0r, v1r;
    {
        const bf16* kp = k + base + (size_t)krow * DP + kd0;
        k0r = *(const bf16x8*)kp; k1r = *(const bf16x8*)(kp + 8);
        const bf16* vp = v + base + (size_t)(2 * pp) * DP + c0;
        v0r = *(const bf16x8*)vp; v1r = *(const bf16x8*)(vp + DP);
    }

    f32x4 o[4] = {z, z, z, z};
    float mi = -1e30f, li = 0.f;

    for (int kt = 0; kt < nkt; ++kt) {
        const int cur = kt & 1;
        const int kk0 = kt * 64;
        *(bf16x8*)&Ks[cur][krow * AST + kd0]     = k0r;
        *(bf16x8*)&Ks[cur][krow * AST + kd0 + 8] = k1r;
        #pragma unroll
        for (int j = 0; j < 8; ++j) {
            bf16x2 pr; pr[0] = v0r[j]; pr[1] = v1r[j];
            *(bf16x2*)&VsT[cur][(c0 + j) * AST + 2 * pp] = pr;
        }
        __syncthreads();
        if (kt + 1 < nkt) {
            const bf16* kp = k + base + (size_t)(kk0 + 64 + krow) * DP + kd0;
            k0r = *(const bf16x8*)kp; k1r = *(const bf16x8*)(kp + 8);
            const bf16* vp = v + base + (size_t)(kk0 + 64 + 2 * pp) * DP + c0;
            v0r = *(const bf16x8*)vp; v1r = *(const bf16x8*)(vp + DP);
        }

        // QK^T swapped: sa[nb][r] = score[key = kk0+nb*16+quad*4+r][q = myq]
        f32x4 sa[4] = {z, z, z, z};
        __builtin_amdgcn_s_setprio(1);
        #pragma unroll
        for (int nb = 0; nb < 4; ++nb)
            #pragma unroll
            for (int c = 0; c < 2; ++c) {
                const bf16x8 kf = *(const bf16x8*)&Ks[cur][(nb * 16 + fr) * AST + c * 32 + quad * 8];
                sa[nb] = mfma16(kf, qf[c], sa[nb]);
            }
        __builtin_amdgcn_s_setprio(0);

        float p[4][4];
        float rmax = -1e30f;
        if (kk0 + 63 > qr0) {   // wave-uniform: tile may touch the mask
            #pragma unroll
            for (int nb = 0; nb < 4; ++nb)
                #pragma unroll
                for (int r = 0; r < 4; ++r) {
                    const int key = kk0 + nb * 16 + quad * 4 + r;
                    float sv = sa[nb][r];
                    if (key > myq) sv += -1e9f;
                    p[nb][r] = sv;
                    rmax = fmaxf(rmax, sv);
                }
        } else {                // fully unmasked tile
            #pragma unroll
            for (int nb = 0; nb < 4; ++nb)
                #pragma unroll
                for (int r = 0; r < 4; ++r) {
                    p[nb][r] = sa[nb][r];
                    rmax = fmaxf(rmax, sa[nb][r]);
                }
        }
        rmax = fmaxf(rmax, __shfl_xor(rmax, 16));
        rmax = fmaxf(rmax, __shfl_xor(rmax, 32));

        // T13 defer-max: rescale only when needed (wave-uniform branch).
        const bool need = !__all(rmax - mi <= 8.0f);
        if (need) {
            const float nm = fmaxf(mi, rmax);
            const float alpha = __expf(mi - nm);
            mi = nm;
            li *= alpha;
            #pragma unroll
            for (int db = 0; db < 4; ++db)
                #pragma unroll
                for (int r = 0; r < 4; ++r) o[db][r] *= alpha;
        }
        float ps = 0.f;
        #pragma unroll
        for (int nb = 0; nb < 4; ++nb)
            #pragma unroll
            for (int r = 0; r < 4; ++r) {
                const float e = __expf(p[nb][r] - mi);
                p[nb][r] = e;
                ps += e;
            }
        ps += __shfl_xor(ps, 16);
        ps += __shfl_xor(ps, 32);
        li += ps;

        // P store: row = q-local (fr), col = key-local (nb*16+quad*4+r).
        #pragma unroll
        for (int nb = 0; nb < 4; ++nb) {
            bf16x4 pw;
            pw[0] = (bf16)p[nb][0]; pw[1] = (bf16)p[nb][1];
            pw[2] = (bf16)p[nb][2]; pw[3] = (bf16)p[nb][3];
            *(bf16x4*)&Ps[wv][fr * AST + nb * 16 + quad * 4] = pw;
        }

        bf16x8 pf[2];
        #pragma unroll
        for (int c = 0; c < 2; ++c)
            pf[c] = *(const bf16x8*)&Ps[wv][fr * AST + c * 32 + quad * 8];
        // PV as O^T = V^T . P^T: D row = d-local (quad*4+r), col = q (fr).
        __builtin_amdgcn_s_setprio(1);
        #pragma unroll
        for (int db = 0; db < 4; ++db)
            #pragma unroll
            for (int c = 0; c < 2; ++c) {
                const bf16x8 vf = *(const bf16x8*)&VsT[cur][(db * 16 + fr) * AST + c * 32 + quad * 8];
                o[db] = mfma16(vf, pf[c], o[db]);
            }
        __builtin_amdgcn_s_setprio(0);
    }

    const float inv_li = 1.0f / li;
    #pragma unroll
    for (int db = 0; db < 4; ++db) {
        bf16x4 ov;
        #pragma unroll
        for (int r = 0; r < 4; ++r) ov[r] = (bf16)(o[db][r] * inv_li);
        const int d = db * 16 + quad * 4;
        *(bf16x4*)&ctx[((size_t)(b * SEQ + myq)) * D_MODEL + hh * DP + d] = ov;
    }
}

// ======================= launcher ==========================================
extern "C" void kernel_launch(void* const* d_in, const int* in_sizes, int n_in,
                              void* d_out, int out_size, void* d_ws, size_t ws_size,
                              hipStream_t stream) {
    const float* x       = (const float*)d_in[0];
    const float* wq_w    = (const float*)d_in[2];
    const float* wq_b    = (const float*)d_in[3];
    const float* wk_w    = (const float*)d_in[4];
    const float* wk_b    = (const float*)d_in[5];
    const float* wv_w    = (const float*)d_in[6];
    const float* wv_b    = (const float*)d_in[7];
    const float* dense_w = (const float*)d_in[8];
    const float* dense_b = (const float*)d_in[9];
    const float* gamma1  = (const float*)d_in[10];
    const float* beta1   = (const float*)d_in[11];
    const float* gamma2  = (const float*)d_in[12];
    const float* beta2   = (const float*)d_in[13];
    const float* fc_w    = (const float*)d_in[14];
    const float* proj_w  = (const float*)d_in[15];
    float* out = (float*)d_out;

    bf16* ws = (bf16*)d_ws;
    const size_t M1 = (size_t)1 << 20;
    bf16* xn   = ws;               // -> h -> hn in place   bytes [0,8MB)
    bf16* qb   = ws + 4 * M1;      // bytes [8,16MB)
    bf16* kb   = ws + 8 * M1;      // bytes [16,24MB)
    bf16* vb   = ws + 12 * M1;     // bytes [24,32MB)
    bf16* ctx  = ws + 16 * M1;     // bytes [32,40MB)
    bf16* ff1  = qb;               // 16M elems overlay: bytes [8,40MB)
    bf16* wqc  = ws + 20 * M1;     // bytes [40,42MB)
    bf16* wkc  = ws + 21 * M1;
    bf16* wvc  = ws + 22 * M1;
    bf16* wdc  = ws + 23 * M1;
    bf16* fcc  = ws + 24 * M1;     // bytes [48,56MB)
    bf16* prjc = ws + 28 * M1;     // bytes [56,64MB)
    bf16* h = xn, *hn = xn;
    // split-K partial 1: 16MB f32 at bytes [40,56MB) = wqc..fcc, all dead at
    // proj time. partial 0 goes to `out`. No overlap with ff1 or prjc.
    float* part1 = (float*)(ws + 20 * M1);

    // fused weight pre-conversion (fp32 -> bf16), one dispatch
    CvtArgs ca;
    ca.in[0] = (const float4*)wq_w;    ca.out[0] = (bf16x4*)wqc;
    ca.in[1] = (const float4*)wk_w;    ca.out[1] = (bf16x4*)wkc;
    ca.in[2] = (const float4*)wv_w;    ca.out[2] = (bf16x4*)wvc;
    ca.in[3] = (const float4*)dense_w; ca.out[3] = (bf16x4*)wdc;
    ca.in[4] = (const float4*)fc_w;    ca.out[4] = (bf16x4*)fcc;
    ca.in[5] = (const float4*)proj_w;  ca.out[5] = (bf16x4*)prjc;
    cvt_all<<<12288, 256, 0, stream>>>(ca);

    ln_kernel<float><<<TOK, 256, 0, stream>>>(x, gamma1, beta1, xn);
    gemm_qkv<<<dim3(24, 32), 256, 0, stream>>>(xn, wqc, wkc, wvc,
                                               wq_b, wk_b, wv_b, qb, kb, vb);
    attn_kernel<<<dim3(32, BB * NH), 256, 0, stream>>>(qb, kb, vb, ctx);
    gemm_bt64<1, bf16><<<dim3(16, 32), 256, 0, stream>>>(
        ctx, wdc, dense_b, xn, h, (bf16*)nullptr, TOK, D_MODEL, D_MODEL, D_MODEL);
    ln_kernel<bf16><<<TOK, 256, 0, stream>>>(h, gamma2, beta2, hn);
    gemm_bt<2, bf16><<<dim3(32, 32), 256, 0, stream>>>(hn, fcc, nullptr, nullptr, ff1,
                                                       TOK, FFD, D_MODEL, 1.0f);
    // proj: split-K x2 -> f32 partials (z=0 -> out, z=1 -> part1), then combine
    gemm_bt64<4, float><<<dim3(16, 32, 2), 256, 0, stream>>>(
        ff1, prjc, nullptr, nullptr, out, part1, TOK, D_MODEL, FFD, FFD / 2);
    combine_add<<<4096, 256, 0, stream>>>(
        (const float4*)part1, (const bf16x4*)hn, (float4*)out);
}